// Round 13
// baseline (108.762 us; speedup 1.0000x reference)
//
#include <hip/hip_runtime.h>
#include <math.h>

// Problem constants (B=2, DIM=192, NH=6, HD=32, S=16, H=32, W=32, WS=4^3)
#define BB    2
#define DIMC  192
#define NHH   6
#define HDD   32
#define NPOS  16384              // S*H*W
#define NWTOT 256                // windows per batch
#define ATT_SCALE 0.17677669529663687f  // 32^-0.5

typedef _Float16 f16x8 __attribute__((ext_vector_type(8)));
typedef _Float16 f16x4 __attribute__((ext_vector_type(4)));
typedef float f32x4 __attribute__((ext_vector_type(4)));

static __device__ __forceinline__ uint2 shfl_u2(uint2 v, int src) {
  uint2 r;
  r.x = (unsigned)__shfl((int)v.x, src, 64);
  r.y = (unsigned)__shfl((int)v.y, src, 64);
  return r;
}

// ---------------------------------------------------------------------------
// 0) prep: fp16 weights (w_qkv 576x192, w_proj 192x192) + LANE-MAJOR bias
//    table biasL[nh][half][m][lane][8]
__global__ void k_prep(const float* __restrict__ wq, const float* __restrict__ wp,
                       const float* __restrict__ rpb_g,
                       _Float16* __restrict__ whq, _Float16* __restrict__ whp,
                       _Float16* __restrict__ biasL) {
  int i = blockIdx.x * 256 + threadIdx.x;
  if (i < 576 * DIMC) {
    whq[i] = (_Float16)wq[i];
  } else if (i < 576 * DIMC + DIMC * DIMC) {
    int j = i - 576 * DIMC;
    whp[j] = (_Float16)wp[j];
  } else {
    int j = i - (576 * DIMC + DIMC * DIMC);
    if (j < 6 * 2 * 4 * 64 * 8) {
      int nh = j >> 12;            // /4096
      int r = j & 4095;
      int hw = r >> 11;
      int r2 = r & 2047;
      int m = r2 >> 9;
      int lane = (r2 >> 3) & 63;
      int e = r2 & 7;
      int ni = e >> 2, ri = e & 3;
      int qt = (hw * 2 + ni) * 16 + (lane & 15);
      int kt = m * 16 + (lane >> 4) * 4 + ri;
      int d0 = (qt >> 4) - (kt >> 4) + 3;
      int d1 = ((qt >> 2) & 3) - ((kt >> 2) & 3) + 3;
      int d2 = (qt & 3) - (kt & 3) + 3;
      biasL[j] = (_Float16)rpb_g[(d0 * 11 + d1 * 7 + d2) * 6 + nh];
    }
  }
}

// ---------------------------------------------------------------------------
// 1+2) FUSED window avg-pool + leaky + offset/scale 1x1 convs.
//      Reads x fp32 channel-major directly (L3-hot: runs after k_qkv).
__global__ __launch_bounds__(256) void k_poolsc(
    const float* __restrict__ x,
    const float* __restrict__ w_off, const float* __restrict__ b_off,
    const float* __restrict__ w_sc, const float* __restrict__ b_sc,
    float* __restrict__ off, float* __restrict__ sc) {
  __shared__ float P[192];
  int bid = blockIdx.x;
  int b = bid >> 8, win = bid & 255;
  int pbase = ((win >> 6) * 4) * 1024 + (((win >> 3) & 7) * 4) * 32 + (win & 7) * 4;
  int tid = threadIdx.x;
  if (tid < DIMC) {
    const float* xb = x + ((size_t)(b * DIMC + tid)) * NPOS + pbase;
    float s = 0.f;
#pragma unroll
    for (int iz = 0; iz < 4; ++iz)
#pragma unroll
      for (int iy = 0; iy < 4; ++iy) {
        float4 v = *(const float4*)(xb + iz * 1024 + iy * 32);
        s += v.x + v.y + v.z + v.w;
      }
    s *= (1.f / 64.f);
    P[tid] = (s >= 0.f) ? s : 0.01f * s;
  }
  __syncthreads();
  if (tid < 36) {
    int kind = (tid >= 18);
    int oo = kind ? tid - 18 : tid;
    const float* wrow = (kind ? w_sc : w_off) + oo * DIMC;
    float acc = (kind ? b_sc : b_off)[oo];
    for (int c = 0; c < DIMC; ++c) acc += wrow[c] * P[c];
    int nh = oo / 3, c3 = oo % 3;
    size_t dst = ((size_t)(b * NHH + nh) * 3 + c3) * NWTOT + win;
    if (!kind) {
      acc *= (c3 == 2) ? 0.25f : 0.125f;
      off[dst] = acc;
    } else {
      sc[dst] = acc;
    }
  }
}

// ---------------------------------------------------------------------------
// 3a) qkv GEMM from fp32 x directly. One block = one 64-col n-slice; B staged
//     fp32->fp16 ONCE (48KB LDS holds full K=192); loop over 9 m-blocks with
//     A-tiles (fp16 weights, L2-resident). Epilogue: split qh/kvh scatter.
//     Both A and B frag reads use XOR ((lrow&7)<<4) -> identical per-lane
//     k-permutation (row bases are multiples of 16) => dot products exact.
__global__ __launch_bounds__(256) void k_qkv(
    const _Float16* __restrict__ A, const float* __restrict__ bias,
    const float* __restrict__ X32,
    _Float16* __restrict__ qh, _Float16* __restrict__ kvh) {
  __shared__ char Bl[64 * 384];    // [n][192 halfs], swizzled
  __shared__ char Al[64 * 384];    // [m][192 halfs], swizzled
  int bz = blockIdx.z;
  int n0 = blockIdx.x * 64;
  int tid = threadIdx.x;
  int wave = tid >> 6, lane = tid & 63;
  int wm = wave >> 1, wn = wave & 1;
  int lrow = lane & 15, lkg = lane >> 4;
  // stage B once: 64 n x 24 k-segs, fp32 k-strided loads coalesced along n
  const float* Xb = X32 + (size_t)bz * DIMC * NPOS;
  for (int c = tid; c < 64 * 24; c += 256) {
    int n = c & 63, kg = c >> 6;
    const float* src = Xb + (size_t)(kg * 8) * NPOS + n0 + n;
    union { _Float16 h[8]; uint4 u; } t;
#pragma unroll
    for (int j = 0; j < 8; ++j) t.h[j] = (_Float16)src[(size_t)j * NPOS];
    *(uint4*)(Bl + n * 384 + ((kg * 16) ^ ((n & 7) << 4))) = t.u;
  }
  for (int mb = 0; mb < 9; ++mb) {
    // stage A m-block (64 x 192 halfs, b128 coalesced)
    __syncthreads();
    for (int c = tid; c < 64 * 24; c += 256) {
      int r = c >> 5, sg2 = c & 31;          // interleave: better store pattern
      int seg = sg2 * 24 / 32;               // not used; keep simple below
      (void)seg;
      break;
    }
    for (int c = tid; c < 64 * 24; c += 256) {
      int r = c & 63, kg = c >> 6;
      uint4 v = *(const uint4*)(A + (size_t)(mb * 64 + r) * DIMC + kg * 8);
      *(uint4*)(Al + r * 384 + ((kg * 16) ^ ((r & 7) << 4))) = v;
    }
    __syncthreads();
    f32x4 acc[2][2] = {};
#pragma unroll
    for (int kc = 0; kc < 3; ++kc)
#pragma unroll
      for (int ks = 0; ks < 2; ++ks) {
        int kb = kc * 128 + ks * 64 + lkg * 16;
        f16x8 af[2], bf[2];
#pragma unroll
        for (int mf = 0; mf < 2; ++mf) {
          int row = wm * 32 + mf * 16 + lrow;
          af[mf] = *(const f16x8*)(Al + row * 384 + (kb ^ ((row & 7) << 4)));
        }
#pragma unroll
        for (int nf = 0; nf < 2; ++nf) {
          int row = wn * 32 + nf * 16 + lrow;
          bf[nf] = *(const f16x8*)(Bl + row * 384 + (kb ^ ((row & 7) << 4)));
        }
#pragma unroll
        for (int mf = 0; mf < 2; ++mf)
#pragma unroll
          for (int nf = 0; nf < 2; ++nf)
            acc[mf][nf] = __builtin_amdgcn_mfma_f32_16x16x32_f16(af[mf], bf[nf], acc[mf][nf], 0, 0, 0);
      }
    // epilogue: scatter to qh / kvh (head-interleaved)
    int crow = lkg * 4, ccol = lrow;
#pragma unroll
    for (int mf = 0; mf < 2; ++mf)
#pragma unroll
      for (int nf = 0; nf < 2; ++nf) {
        int m = mb * 64 + wm * 32 + mf * 16 + crow;
        int n = n0 + wn * 32 + nf * 16 + ccol;
        union { _Float16 h[4]; uint2 u; } pk;
#pragma unroll
        for (int r = 0; r < 4; ++r) pk.h[r] = (_Float16)(acc[mf][nf][r] + bias[m + r]);
        size_t rowi = (size_t)bz * NPOS + n;
        _Float16* dst;
        if (m < 192) dst = qh + rowi * 192 + m;
        else if (m < 384) { int mm = m - 192; dst = kvh + rowi * 384 + (mm >> 5) * 64 + (mm & 31); }
        else              { int mm = m - 384; dst = kvh + rowi * 384 + (mm >> 5) * 64 + 32 + (mm & 31); }
        *(uint2*)dst = pk.u;
      }
  }
}

// ---------------------------------------------------------------------------
// 3b) proj GEMM (fp16 MFMA): out[b](192xN) = whp @ pin[b][n][192]^T + bias
__global__ __launch_bounds__(256) void k_gemmP(
    const _Float16* __restrict__ A, const float* __restrict__ bias,
    const _Float16* __restrict__ Bm, float* __restrict__ Y32, int M, int N) {
  const int K = DIMC;
  int bz = blockIdx.z;
  int n0 = blockIdx.x * 128, m0 = blockIdx.y * 64;
  const _Float16* Bb = Bm + (size_t)bz * N * K;
  __shared__ _Float16 Al[64 * 64];
  __shared__ _Float16 Bl[128 * 64];
  int tid = threadIdx.x;
  int wave = tid >> 6, lane = tid & 63;
  int wm = wave >> 1, wn = wave & 1;
  int lrow = lane & 15, lkg = lane >> 4;
  f32x4 acc[2][4] = {};
  for (int k0 = 0; k0 < K; k0 += 64) {
    for (int c = tid; c < 512; c += 256) {
      int r = c >> 3, seg = c & 7;
      uint4 v = *(const uint4*)(A + (size_t)(m0 + r) * K + k0 + seg * 8);
      *(uint4*)((char*)Al + r * 128 + ((seg * 16) ^ ((r & 7) << 4))) = v;
    }
    for (int c = tid; c < 1024; c += 256) {
      int r = c >> 3, seg = c & 7;
      uint4 v = *(const uint4*)(Bb + (size_t)(n0 + r) * K + k0 + seg * 8);
      *(uint4*)((char*)Bl + r * 128 + ((seg * 16) ^ ((r & 7) << 4))) = v;
    }
    __syncthreads();
#pragma unroll
    for (int ks = 0; ks < 2; ++ks) {
      f16x8 af[2], bf[4];
#pragma unroll
      for (int mf = 0; mf < 2; ++mf) {
        int row = wm * 32 + mf * 16 + lrow;
        af[mf] = *(const f16x8*)((const char*)Al + row * 128 +
                                 ((ks * 64 + lkg * 16) ^ ((row & 7) << 4)));
      }
#pragma unroll
      for (int nf = 0; nf < 4; ++nf) {
        int row = wn * 64 + nf * 16 + lrow;
        bf[nf] = *(const f16x8*)((const char*)Bl + row * 128 +
                                 ((ks * 64 + lkg * 16) ^ ((row & 7) << 4)));
      }
#pragma unroll
      for (int mf = 0; mf < 2; ++mf)
#pragma unroll
        for (int nf = 0; nf < 4; ++nf)
          acc[mf][nf] = __builtin_amdgcn_mfma_f32_16x16x32_f16(af[mf], bf[nf], acc[mf][nf], 0, 0, 0);
    }
    __syncthreads();
  }
  int crow = lkg * 4, ccol = lrow;
#pragma unroll
  for (int mf = 0; mf < 2; ++mf)
#pragma unroll
    for (int nf = 0; nf < 4; ++nf) {
      int m = m0 + wm * 32 + mf * 16 + crow;
      int n = n0 + wn * 64 + nf * 16 + ccol;
#pragma unroll
      for (int r = 0; r < 4; ++r)
        Y32[(size_t)bz * M * N + (size_t)(m + r) * N + n] = acc[mf][nf][r] + bias[m + r];
    }
}

// ---------------------------------------------------------------------------
// 4) FUSED deformable grid-sample + windowed attention (r12, unchanged).
__global__ __launch_bounds__(128, 6) void k_sattn(
    const _Float16* __restrict__ qh, const _Float16* __restrict__ kvh,
    const float* __restrict__ off, const float* __restrict__ sc,
    const _Float16* __restrict__ biasL,
    _Float16* __restrict__ pin) {
  __shared__ char Kl[4096];          // [64tok][32hd], chunk^((tok>>1)&3)
  __shared__ char Vt[4096];          // [32hd][64tok], (tok*2)^((hd&7)<<4)
  __shared__ unsigned ci_lds[64][8]; // packed (w16<<16)|posidx per (tok,corner)
  int bid = blockIdx.x;
  int swz = (bid & 7) * 384 + (bid >> 3);   // 3072 = 8*384, bijective XCD chunks
  int nh = swz % 6;
  int t6 = swz / 6;
  int win = t6 & 255;
  int b = t6 >> 8;
  int bnh = b * NHH + nh;
  int tid = threadIdx.x;
  int lane = tid & 63, halfw = tid >> 6;
  int cl = lane & 15, g = lane >> 4;
  int pbase = ((win >> 6) * 4) * 1024 + (((win >> 3) & 7) * 4) * 32 + (win & 7) * 4;
  int prow = (cl >> 2) * 32 + (cl & 3);
  int n0 = halfw * 2;                // this wave's q-column block base
  f16x8 qf[2];
  const _Float16* qbase = qh + ((size_t)b * NPOS) * 192 + nh * 32 + g * 8;
#pragma unroll
  for (int ni = 0; ni < 2; ++ni)
    qf[ni] = *(const f16x8*)(qbase + (size_t)(pbase + (n0 + ni) * 1024 + prow) * 192);
  f16x8 bm[4];
  {
    const _Float16* bl = biasL + ((size_t)(nh * 2 + halfw) * 4) * 512 + lane * 8;
#pragma unroll
    for (int m = 0; m < 4; ++m) bm[m] = *(const f16x8*)(bl + m * 512);
  }
  if (halfw == 0) {
    int tok = lane;
    int is = tok >> 4, ih = (tok >> 2) & 3, iw = tok & 3;
    int s = (win >> 6) * 4 + is, h = ((win >> 3) & 7) * 4 + ih, w = (win & 7) * 4 + iw;
    const float* ob = off + ((size_t)bnh * 3) * NWTOT + win;
    const float* sb = sc + ((size_t)bnh * 3) * NWTOT + win;
    float o0 = ob[0], o1 = ob[NWTOT], o2 = ob[2 * NWTOT];
    float s0 = sb[0], s1 = sb[NWTOT], s2 = sb[2 * NWTOT];
    float gxn = -1.f + 2.f * w / 31.f + ((2.f * iw - 3.f) / 31.f) * s0 + o0;
    float gyn = -1.f + 2.f * h / 31.f + ((2.f * ih - 3.f) / 31.f) * s1 + o1;
    float gzn = -1.f + 2.f * s / 15.f + ((2.f * is - 3.f) / 15.f) * s2 + o2;
    float gx = (gxn + 1.f) * 15.5f;
    float gy = (gyn + 1.f) * 15.5f;
    float gz = (gzn + 1.f) * 7.5f;
    float x0f = floorf(gx), y0f = floorf(gy), z0f = floorf(gz);
    float fx = gx - x0f, fy = gy - y0f, fz = gz - z0f;
    int x0 = (int)x0f, y0 = (int)y0f, z0 = (int)z0f;
    int n = 0;
    for (int dz = 0; dz < 2; ++dz)
      for (int dy = 0; dy < 2; ++dy)
        for (int dx = 0; dx < 2; ++dx) {
          int zz = z0 + dz, yy = y0 + dy, xx = x0 + dx;
          bool valid = (zz >= 0 && zz < 16 && yy >= 0 && yy < 32 && xx >= 0 && xx < 32);
          int zc = min(max(zz, 0), 15), yc = min(max(yy, 0), 31), xc = min(max(xx, 0), 31);
          float wgt = (dz ? fz : 1.f - fz) * (dy ? fy : 1.f - fy) * (dx ? fx : 1.f - fx);
          union { _Float16 h; unsigned short u; } wc;
          wc.h = (_Float16)(valid ? wgt : 0.f);
          ci_lds[tok][n] = ((unsigned)wc.u << 16) | (unsigned)(zc * 1024 + yc * 32 + xc);
          ++n;
        }
  }
  __syncthreads();
  int tbase = (halfw << 5) + (lane >> 3);
  int chk = lane & 7;
  unsigned cpk[8][4];
#pragma unroll
  for (int j = 0; j < 8; ++j)
#pragma unroll
    for (int tg = 0; tg < 4; ++tg)
      cpk[j][tg] = ci_lds[tbase + tg * 8][j];
  const _Float16* kvbase = kvh + (size_t)b * NPOS * 384 + nh * 64 + chk * 8;
  f16x8 acc[4] = {};
#pragma unroll
  for (int j = 0; j < 8; ++j)
#pragma unroll
    for (int tg = 0; tg < 4; ++tg) {
      unsigned pkd = cpk[j][tg];
      f16x8 v = *(const f16x8*)(kvbase + (size_t)(pkd & 0xFFFFu) * 384);
      union { unsigned short u; _Float16 h; } wc;
      wc.u = (unsigned short)(pkd >> 16);
      _Float16 wv = wc.h;
      f16x8 w8 = {wv, wv, wv, wv, wv, wv, wv, wv};
      acc[tg] += v * w8;
    }
  if (chk < 4) {
#pragma unroll
    for (int tg = 0; tg < 4; ++tg) {
      int t = tbase + tg * 8;
      *(f16x8*)(Kl + t * 64 + ((chk ^ ((t >> 1) & 3)) * 16)) = acc[tg];
    }
  } else {
    int cV = chk - 4;
#pragma unroll
    for (int tg = 0; tg < 4; ++tg) {
      int t = tbase + tg * 8;
#pragma unroll
      for (int e = 0; e < 8; ++e) {
        int hd = cV * 8 + e;
        *(_Float16*)(Vt + hd * 128 + ((t * 2) ^ ((hd & 7) << 4))) = acc[tg][e];
      }
    }
  }
  __syncthreads();
  f16x8 kf[4];
#pragma unroll
  for (int m = 0; m < 4; ++m) {
    int r = m * 16 + cl;
    kf[m] = *(const f16x8*)(Kl + r * 64 + ((g ^ ((r >> 1) & 3)) * 16));
  }
  f32x4 accT[4][2] = {};
  __builtin_amdgcn_s_setprio(1);
#pragma unroll
  for (int m = 0; m < 4; ++m)
#pragma unroll
    for (int ni = 0; ni < 2; ++ni)
      accT[m][ni] = __builtin_amdgcn_mfma_f32_16x16x32_f16(kf[m], qf[ni], accT[m][ni], 0, 0, 0);
  __builtin_amdgcn_s_setprio(0);
#pragma unroll
  for (int m = 0; m < 4; ++m)
#pragma unroll
    for (int ni = 0; ni < 2; ++ni)
#pragma unroll
      for (int ri = 0; ri < 4; ++ri)
        accT[m][ni][ri] = accT[m][ni][ri] * ATT_SCALE + (float)bm[m][ni * 4 + ri];
  uint2 pk[4][2];
#pragma unroll
  for (int ni = 0; ni < 2; ++ni) {
    float mx = -1e30f;
#pragma unroll
    for (int m = 0; m < 4; ++m)
#pragma unroll
      for (int ri = 0; ri < 4; ++ri) mx = fmaxf(mx, accT[m][ni][ri]);
    mx = fmaxf(mx, __shfl_xor(mx, 16));
    mx = fmaxf(mx, __shfl_xor(mx, 32));
    float sm = 0.f;
#pragma unroll
    for (int m = 0; m < 4; ++m)
#pragma unroll
      for (int ri = 0; ri < 4; ++ri) {
        float e = __expf(accT[m][ni][ri] - mx);
        accT[m][ni][ri] = e;
        sm += e;
      }
    sm += __shfl_xor(sm, 16);
    sm += __shfl_xor(sm, 32);
    float inv = 1.f / sm;
#pragma unroll
    for (int m = 0; m < 4; ++m) {
      union { _Float16 h[4]; uint2 u; } t;
#pragma unroll
      for (int ri = 0; ri < 4; ++ri) t.h[ri] = (_Float16)(accT[m][ni][ri] * inv);
      pk[m][ni] = t.u;
    }
  }
  int src_lo = ((g & 1) << 5) + cl;
  int src_hi = src_lo + 16;
  int msel = g >> 1;
  f32x4 accO[2][2] = {};
#pragma unroll
  for (int ks = 0; ks < 2; ++ks) {
    f16x8 va[2];
#pragma unroll
    for (int m2 = 0; m2 < 2; ++m2) {
      int hd = m2 * 16 + cl;
      va[m2] = *(const f16x8*)(Vt + hd * 128 + ((ks * 64 + g * 16) ^ ((hd & 7) << 4)));
    }
#pragma unroll
    for (int ni = 0; ni < 2; ++ni) {
      uint2 a0 = shfl_u2(pk[2 * ks][ni], src_lo);
      uint2 a1 = shfl_u2(pk[2 * ks + 1][ni], src_lo);
      uint2 b0 = shfl_u2(pk[2 * ks][ni], src_hi);
      uint2 b1 = shfl_u2(pk[2 * ks + 1][ni], src_hi);
      union { uint2 lohi[2]; f16x8 f; } u;
      u.lohi[0] = msel ? a1 : a0;
      u.lohi[1] = msel ? b1 : b0;
      __builtin_amdgcn_s_setprio(1);
#pragma unroll
      for (int m2 = 0; m2 < 2; ++m2)
        accO[m2][ni] = __builtin_amdgcn_mfma_f32_16x16x32_f16(va[m2], u.f, accO[m2][ni], 0, 0, 0);
      __builtin_amdgcn_s_setprio(0);
    }
  }
  _Float16* pb = pin + ((size_t)b * NPOS) * DIMC + nh * 32 + g * 4;
#pragma unroll
  for (int ni = 0; ni < 2; ++ni) {
    _Float16* dst = pb + (size_t)(pbase + (n0 + ni) * 1024 + prow) * DIMC;
#pragma unroll
    for (int m2 = 0; m2 < 2; ++m2) {
      union { _Float16 h[4]; uint2 u; } pkk;
#pragma unroll
      for (int r = 0; r < 4; ++r) pkk.h[r] = (_Float16)accO[m2][ni][r];
      *(uint2*)(dst + m2 * 16) = pkk.u;
    }
  }
}

// ---------------------------------------------------------------------------
extern "C" void kernel_launch(void* const* d_in, const int* in_sizes, int n_in,
                              void* d_out, int out_size, void* d_ws, size_t ws_size,
                              hipStream_t stream) {
  const float* x      = (const float*)d_in[0];
  const float* w_qkv  = (const float*)d_in[2];
  const float* b_qkv  = (const float*)d_in[3];
  const float* w_off  = (const float*)d_in[4];
  const float* b_off  = (const float*)d_in[5];
  const float* w_sc   = (const float*)d_in[6];
  const float* b_sc   = (const float*)d_in[7];
  const float* w_proj = (const float*)d_in[8];
  const float* b_proj = (const float*)d_in[9];
  const float* rpb    = (const float*)d_in[10];
  float* out = (float*)d_out;
  char* wsp = (char*)d_ws;

  _Float16* qhb = (_Float16*)wsp;                       wsp += (size_t)BB * NPOS * 192 * 2;
  _Float16* kvh = (_Float16*)wsp;                       wsp += (size_t)BB * NPOS * 384 * 2;
  _Float16* pin = (_Float16*)wsp;                       wsp += (size_t)BB * NPOS * DIMC * 2;
  _Float16* whq = (_Float16*)wsp;                       wsp += (size_t)576 * DIMC * 2;
  _Float16* whp = (_Float16*)wsp;                       wsp += (size_t)DIMC * DIMC * 2;
  _Float16* biasL = (_Float16*)wsp;                     wsp += (size_t)6 * 2 * 4 * 64 * 8 * 2;
  float* offb   = (float*)wsp;                          wsp += (size_t)BB * NHH * 3 * NWTOT * 4;
  float* scb    = (float*)wsp;

  k_prep<<<672, 256, 0, stream>>>(w_qkv, w_proj, rpb, whq, whp, biasL);
  k_qkv<<<dim3(NPOS / 64, 1, BB), 256, 0, stream>>>(whq, b_qkv, x, qhb, kvh);
  k_poolsc<<<BB * NWTOT, 256, 0, stream>>>(x, w_off, b_off, w_sc, b_sc, offb, scb);
  k_sattn<<<3072, 128, 0, stream>>>(qhb, kvh, offb, scb, biasL, pin);
  k_gemmP<<<dim3(NPOS / 128, DIMC / 64, BB), 256, 0, stream>>>(
      whp, b_proj, pin, out, DIMC, NPOS);
}

// Round 14
// 78.873 us; speedup vs baseline: 1.3790x; 1.3790x over previous
//
#include <hip/hip_runtime.h>
#include <math.h>

// Problem constants (B=2, DIM=192, NH=6, HD=32, S=16, H=32, W=32, WS=4^3)
#define BB    2
#define DIMC  192
#define NHH   6
#define HDD   32
#define NPOS  16384              // S*H*W
#define NWTOT 256                // windows per batch
#define ATT_SCALE 0.17677669529663687f  // 32^-0.5

typedef _Float16 f16x8 __attribute__((ext_vector_type(8)));
typedef _Float16 f16x4 __attribute__((ext_vector_type(4)));
typedef float f32x4 __attribute__((ext_vector_type(4)));

static __device__ __forceinline__ uint2 shfl_u2(uint2 v, int src) {
  uint2 r;
  r.x = (unsigned)__shfl((int)v.x, src, 64);
  r.y = (unsigned)__shfl((int)v.y, src, 64);
  return r;
}

// ---------------------------------------------------------------------------
// 0) COMBINED: transpose x -> xt fp16 (blocks 0..6143) + weight/bias prep
//    (blocks 6144..6815).  biasL[nh][half][m][lane][8] lane-major.
#define NTRX (BB * 24 * NPOS / 256)   // 6144
__global__ void k_prepx(const float* __restrict__ x, _Float16* __restrict__ xt,
                        const float* __restrict__ wq, const float* __restrict__ wp,
                        const float* __restrict__ rpb_g,
                        _Float16* __restrict__ whq, _Float16* __restrict__ whp,
                        _Float16* __restrict__ biasL) {
  if (blockIdx.x < NTRX) {
    int idx = blockIdx.x * 256 + threadIdx.x;
    int p = idx & (NPOS - 1);
    int t = idx >> 14;
    int cseg = t % 24;
    int b = t / 24;
    const float* src = x + ((size_t)b * DIMC + cseg * 8) * NPOS + p;
    _Float16 v[8];
#pragma unroll
    for (int j = 0; j < 8; ++j) v[j] = (_Float16)src[(size_t)j * NPOS];
    *(uint4*)(xt + ((size_t)b * NPOS + p) * DIMC + cseg * 8) = *(uint4*)v;
    return;
  }
  int i = (blockIdx.x - NTRX) * 256 + threadIdx.x;
  if (i < 576 * DIMC) {
    whq[i] = (_Float16)wq[i];
  } else if (i < 576 * DIMC + DIMC * DIMC) {
    int j = i - 576 * DIMC;
    whp[j] = (_Float16)wp[j];
  } else {
    int j = i - (576 * DIMC + DIMC * DIMC);
    if (j < 6 * 2 * 4 * 64 * 8) {
      int nh = j >> 12;
      int r = j & 4095;
      int hw = r >> 11;
      int r2 = r & 2047;
      int m = r2 >> 9;
      int lane = (r2 >> 3) & 63;
      int e = r2 & 7;
      int ni = e >> 2, ri = e & 3;
      int qt = (hw * 2 + ni) * 16 + (lane & 15);
      int kt = m * 16 + (lane >> 4) * 4 + ri;
      int d0 = (qt >> 4) - (kt >> 4) + 3;
      int d1 = ((qt >> 2) & 3) - ((kt >> 2) & 3) + 3;
      int d2 = (qt & 3) - (kt & 3) + 3;
      biasL[j] = (_Float16)rpb_g[(d0 * 11 + d1 * 7 + d2) * 6 + nh];
    }
  }
}

// ---------------------------------------------------------------------------
// 1+2) FUSED window avg-pool + leaky + offset/scale 1x1 convs (reads xt).
__global__ __launch_bounds__(256) void k_poolsc(
    const _Float16* __restrict__ xt,
    const float* __restrict__ w_off, const float* __restrict__ b_off,
    const float* __restrict__ w_sc, const float* __restrict__ b_sc,
    float* __restrict__ off, float* __restrict__ sc) {
  __shared__ _Float16 X[64][208];
  __shared__ float P[192];
  int bid = blockIdx.x;
  int b = bid >> 8, win = bid & 255;
  int pbase = ((win >> 6) * 4) * 1024 + (((win >> 3) & 7) * 4) * 32 + (win & 7) * 4;
  int tid = threadIdx.x;
  {
    int tok = tid >> 2, part = tid & 3;
    int pp = pbase + (tok >> 4) * 1024 + ((tok >> 2) & 3) * 32 + (tok & 3);
    const _Float16* src = xt + ((size_t)b * NPOS + pp) * DIMC + part * 48;
#pragma unroll
    for (int s = 0; s < 6; ++s)
      *(uint4*)(&X[tok][part * 48 + s * 8]) = *(const uint4*)(src + s * 8);
  }
  __syncthreads();
  if (tid < DIMC) {
    float acc = 0.f;
#pragma unroll 8
    for (int t = 0; t < 64; ++t) acc += (float)X[t][tid];
    acc *= (1.f / 64.f);
    P[tid] = (acc >= 0.f) ? acc : 0.01f * acc;
  }
  __syncthreads();
  if (tid < 36) {
    int kind = (tid >= 18);
    int oo = kind ? tid - 18 : tid;
    const float* wrow = (kind ? w_sc : w_off) + oo * DIMC;
    float acc = (kind ? b_sc : b_off)[oo];
    for (int c = 0; c < DIMC; ++c) acc += wrow[c] * P[c];
    int nh = oo / 3, c3 = oo % 3;
    size_t dst = ((size_t)(b * NHH + nh) * 3 + c3) * NWTOT + win;
    if (!kind) {
      acc *= (c3 == 2) ? 0.25f : 0.125f;
      off[dst] = acc;
    } else {
      sc[dst] = acc;
    }
  }
}

// ---------------------------------------------------------------------------
// 3) fp16 MFMA GEMM:  Y[b](MxN) = A(MxK=192) @ Bm[b]^T + bias
//    MODE 0: B = pin fp16 [b][n][192]; out fp32 [b][m][N].
//    MODE 1: B = xt fp16 [b][n][192]; out split -> qh[pos][192] fp16 +
//            kvh[pos][nh][K32|V32] fp16 (head-interleaved).
template <int MODE>
__global__ __launch_bounds__(256) void k_gemm16(
    const _Float16* __restrict__ A, const float* __restrict__ bias,
    const _Float16* __restrict__ Bm, float* __restrict__ Y32,
    _Float16* __restrict__ qh, _Float16* __restrict__ kvh, int M, int N) {
  const int K = DIMC;
  int bz = blockIdx.z;
  int n0 = blockIdx.x * 128, m0 = blockIdx.y * 64;
  const _Float16* Bb = Bm + (size_t)bz * N * K;
  __shared__ _Float16 Al[64 * 64];
  __shared__ _Float16 Bl[128 * 64];
  int tid = threadIdx.x;
  int wave = tid >> 6, lane = tid & 63;
  int wm = wave >> 1, wn = wave & 1;
  int lrow = lane & 15, lkg = lane >> 4;
  f32x4 acc[2][4] = {};
  for (int k0 = 0; k0 < K; k0 += 64) {
    for (int c = tid; c < 512; c += 256) {
      int r = c >> 3, seg = c & 7;
      uint4 v = *(const uint4*)(A + (size_t)(m0 + r) * K + k0 + seg * 8);
      *(uint4*)((char*)Al + r * 128 + ((seg * 16) ^ ((r & 7) << 4))) = v;
    }
    for (int c = tid; c < 1024; c += 256) {
      int r = c >> 3, seg = c & 7;
      uint4 v = *(const uint4*)(Bb + (size_t)(n0 + r) * K + k0 + seg * 8);
      *(uint4*)((char*)Bl + r * 128 + ((seg * 16) ^ ((r & 7) << 4))) = v;
    }
    __syncthreads();
#pragma unroll
    for (int ks = 0; ks < 2; ++ks) {
      f16x8 af[2], bf[4];
#pragma unroll
      for (int mf = 0; mf < 2; ++mf) {
        int row = wm * 32 + mf * 16 + lrow;
        af[mf] = *(const f16x8*)((const char*)Al + row * 128 +
                                 ((ks * 64 + lkg * 16) ^ ((row & 7) << 4)));
      }
#pragma unroll
      for (int nf = 0; nf < 4; ++nf) {
        int row = wn * 64 + nf * 16 + lrow;
        bf[nf] = *(const f16x8*)((const char*)Bl + row * 128 +
                                 ((ks * 64 + lkg * 16) ^ ((row & 7) << 4)));
      }
#pragma unroll
      for (int mf = 0; mf < 2; ++mf)
#pragma unroll
        for (int nf = 0; nf < 4; ++nf)
          acc[mf][nf] = __builtin_amdgcn_mfma_f32_16x16x32_f16(af[mf], bf[nf], acc[mf][nf], 0, 0, 0);
    }
    __syncthreads();
  }
  int crow = lkg * 4, ccol = lrow;
#pragma unroll
  for (int mf = 0; mf < 2; ++mf)
#pragma unroll
    for (int nf = 0; nf < 4; ++nf) {
      int m = m0 + wm * 32 + mf * 16 + crow;
      int n = n0 + wn * 64 + nf * 16 + ccol;
      if (MODE == 1) {
        union { _Float16 h[4]; uint2 u; } pk;
#pragma unroll
        for (int r = 0; r < 4; ++r) pk.h[r] = (_Float16)(acc[mf][nf][r] + bias[m + r]);
        size_t rowi = (size_t)bz * NPOS + n;
        _Float16* dst;
        if (m < 192) dst = qh + rowi * 192 + m;
        else if (m < 384) { int mm = m - 192; dst = kvh + rowi * 384 + (mm >> 5) * 64 + (mm & 31); }
        else              { int mm = m - 384; dst = kvh + rowi * 384 + (mm >> 5) * 64 + 32 + (mm & 31); }
        *(uint2*)dst = pk.u;
      } else {
#pragma unroll
        for (int r = 0; r < 4; ++r)
          Y32[(size_t)bz * M * N + (size_t)(m + r) * N + n] = acc[mf][nf][r] + bias[m + r];
      }
    }
}

// ---------------------------------------------------------------------------
// 4) FUSED deformable grid-sample + windowed attention, COALESCED GATHER.
//    r12 structure (packed idx|weight corner table), unchanged.
__global__ __launch_bounds__(128, 6) void k_sattn(
    const _Float16* __restrict__ qh, const _Float16* __restrict__ kvh,
    const float* __restrict__ off, const float* __restrict__ sc,
    const _Float16* __restrict__ biasL,
    _Float16* __restrict__ pin) {
  __shared__ char Kl[4096];          // [64tok][32hd], chunk^((tok>>1)&3)
  __shared__ char Vt[4096];          // [32hd][64tok], (tok*2)^((hd&7)<<4)
  __shared__ unsigned ci_lds[64][8]; // packed (w16<<16)|posidx per (tok,corner)
  int bid = blockIdx.x;
  int swz = (bid & 7) * 384 + (bid >> 3);   // 3072 = 8*384, bijective XCD chunks
  int nh = swz % 6;
  int t6 = swz / 6;
  int win = t6 & 255;
  int b = t6 >> 8;
  int bnh = b * NHH + nh;
  int tid = threadIdx.x;
  int lane = tid & 63, halfw = tid >> 6;
  int cl = lane & 15, g = lane >> 4;
  int pbase = ((win >> 6) * 4) * 1024 + (((win >> 3) & 7) * 4) * 32 + (win & 7) * 4;
  int prow = (cl >> 2) * 32 + (cl & 3);
  int n0 = halfw * 2;                // this wave's q-column block base
  f16x8 qf[2];
  const _Float16* qbase = qh + ((size_t)b * NPOS) * 192 + nh * 32 + g * 8;
#pragma unroll
  for (int ni = 0; ni < 2; ++ni)
    qf[ni] = *(const f16x8*)(qbase + (size_t)(pbase + (n0 + ni) * 1024 + prow) * 192);
  f16x8 bm[4];
  {
    const _Float16* bl = biasL + ((size_t)(nh * 2 + halfw) * 4) * 512 + lane * 8;
#pragma unroll
    for (int m = 0; m < 4; ++m) bm[m] = *(const f16x8*)(bl + m * 512);
  }
  if (halfw == 0) {
    int tok = lane;
    int is = tok >> 4, ih = (tok >> 2) & 3, iw = tok & 3;
    int s = (win >> 6) * 4 + is, h = ((win >> 3) & 7) * 4 + ih, w = (win & 7) * 4 + iw;
    const float* ob = off + ((size_t)bnh * 3) * NWTOT + win;
    const float* sb = sc + ((size_t)bnh * 3) * NWTOT + win;
    float o0 = ob[0], o1 = ob[NWTOT], o2 = ob[2 * NWTOT];
    float s0 = sb[0], s1 = sb[NWTOT], s2 = sb[2 * NWTOT];
    float gxn = -1.f + 2.f * w / 31.f + ((2.f * iw - 3.f) / 31.f) * s0 + o0;
    float gyn = -1.f + 2.f * h / 31.f + ((2.f * ih - 3.f) / 31.f) * s1 + o1;
    float gzn = -1.f + 2.f * s / 15.f + ((2.f * is - 3.f) / 15.f) * s2 + o2;
    float gx = (gxn + 1.f) * 15.5f;
    float gy = (gyn + 1.f) * 15.5f;
    float gz = (gzn + 1.f) * 7.5f;
    float x0f = floorf(gx), y0f = floorf(gy), z0f = floorf(gz);
    float fx = gx - x0f, fy = gy - y0f, fz = gz - z0f;
    int x0 = (int)x0f, y0 = (int)y0f, z0 = (int)z0f;
    int n = 0;
    for (int dz = 0; dz < 2; ++dz)
      for (int dy = 0; dy < 2; ++dy)
        for (int dx = 0; dx < 2; ++dx) {
          int zz = z0 + dz, yy = y0 + dy, xx = x0 + dx;
          bool valid = (zz >= 0 && zz < 16 && yy >= 0 && yy < 32 && xx >= 0 && xx < 32);
          int zc = min(max(zz, 0), 15), yc = min(max(yy, 0), 31), xc = min(max(xx, 0), 31);
          float wgt = (dz ? fz : 1.f - fz) * (dy ? fy : 1.f - fy) * (dx ? fx : 1.f - fx);
          union { _Float16 h; unsigned short u; } wc;
          wc.h = (_Float16)(valid ? wgt : 0.f);
          ci_lds[tok][n] = ((unsigned)wc.u << 16) | (unsigned)(zc * 1024 + yc * 32 + xc);
          ++n;
        }
  }
  __syncthreads();
  int tbase = (halfw << 5) + (lane >> 3);
  int chk = lane & 7;
  unsigned cpk[8][4];
#pragma unroll
  for (int j = 0; j < 8; ++j)
#pragma unroll
    for (int tg = 0; tg < 4; ++tg)
      cpk[j][tg] = ci_lds[tbase + tg * 8][j];
  const _Float16* kvbase = kvh + (size_t)b * NPOS * 384 + nh * 64 + chk * 8;
  f16x8 acc[4] = {};
#pragma unroll
  for (int j = 0; j < 8; ++j)
#pragma unroll
    for (int tg = 0; tg < 4; ++tg) {
      unsigned pkd = cpk[j][tg];
      f16x8 v = *(const f16x8*)(kvbase + (size_t)(pkd & 0xFFFFu) * 384);
      union { unsigned short u; _Float16 h; } wc;
      wc.u = (unsigned short)(pkd >> 16);
      _Float16 wv = wc.h;
      f16x8 w8 = {wv, wv, wv, wv, wv, wv, wv, wv};
      acc[tg] += v * w8;
    }
  if (chk < 4) {
#pragma unroll
    for (int tg = 0; tg < 4; ++tg) {
      int t = tbase + tg * 8;
      *(f16x8*)(Kl + t * 64 + ((chk ^ ((t >> 1) & 3)) * 16)) = acc[tg];
    }
  } else {
    int cV = chk - 4;
#pragma unroll
    for (int tg = 0; tg < 4; ++tg) {
      int t = tbase + tg * 8;
#pragma unroll
      for (int e = 0; e < 8; ++e) {
        int hd = cV * 8 + e;
        *(_Float16*)(Vt + hd * 128 + ((t * 2) ^ ((hd & 7) << 4))) = acc[tg][e];
      }
    }
  }
  __syncthreads();
  f16x8 kf[4];
#pragma unroll
  for (int m = 0; m < 4; ++m) {
    int r = m * 16 + cl;
    kf[m] = *(const f16x8*)(Kl + r * 64 + ((g ^ ((r >> 1) & 3)) * 16));
  }
  f32x4 accT[4][2] = {};
  __builtin_amdgcn_s_setprio(1);
#pragma unroll
  for (int m = 0; m < 4; ++m)
#pragma unroll
    for (int ni = 0; ni < 2; ++ni)
      accT[m][ni] = __builtin_amdgcn_mfma_f32_16x16x32_f16(kf[m], qf[ni], accT[m][ni], 0, 0, 0);
  __builtin_amdgcn_s_setprio(0);
#pragma unroll
  for (int m = 0; m < 4; ++m)
#pragma unroll
    for (int ni = 0; ni < 2; ++ni)
#pragma unroll
      for (int ri = 0; ri < 4; ++ri)
        accT[m][ni][ri] = accT[m][ni][ri] * ATT_SCALE + (float)bm[m][ni * 4 + ri];
  uint2 pk[4][2];
#pragma unroll
  for (int ni = 0; ni < 2; ++ni) {
    float mx = -1e30f;
#pragma unroll
    for (int m = 0; m < 4; ++m)
#pragma unroll
      for (int ri = 0; ri < 4; ++ri) mx = fmaxf(mx, accT[m][ni][ri]);
    mx = fmaxf(mx, __shfl_xor(mx, 16));
    mx = fmaxf(mx, __shfl_xor(mx, 32));
    float sm = 0.f;
#pragma unroll
    for (int m = 0; m < 4; ++m)
#pragma unroll
      for (int ri = 0; ri < 4; ++ri) {
        float e = __expf(accT[m][ni][ri] - mx);
        accT[m][ni][ri] = e;
        sm += e;
      }
    sm += __shfl_xor(sm, 16);
    sm += __shfl_xor(sm, 32);
    float inv = 1.f / sm;
#pragma unroll
    for (int m = 0; m < 4; ++m) {
      union { _Float16 h[4]; uint2 u; } t;
#pragma unroll
      for (int ri = 0; ri < 4; ++ri) t.h[ri] = (_Float16)(accT[m][ni][ri] * inv);
      pk[m][ni] = t.u;
    }
  }
  int src_lo = ((g & 1) << 5) + cl;
  int src_hi = src_lo + 16;
  int msel = g >> 1;
  f32x4 accO[2][2] = {};
#pragma unroll
  for (int ks = 0; ks < 2; ++ks) {
    f16x8 va[2];
#pragma unroll
    for (int m2 = 0; m2 < 2; ++m2) {
      int hd = m2 * 16 + cl;
      va[m2] = *(const f16x8*)(Vt + hd * 128 + ((ks * 64 + g * 16) ^ ((hd & 7) << 4)));
    }
#pragma unroll
    for (int ni = 0; ni < 2; ++ni) {
      uint2 a0 = shfl_u2(pk[2 * ks][ni], src_lo);
      uint2 a1 = shfl_u2(pk[2 * ks + 1][ni], src_lo);
      uint2 b0 = shfl_u2(pk[2 * ks][ni], src_hi);
      uint2 b1 = shfl_u2(pk[2 * ks + 1][ni], src_hi);
      union { uint2 lohi[2]; f16x8 f; } u;
      u.lohi[0] = msel ? a1 : a0;
      u.lohi[1] = msel ? b1 : b0;
      __builtin_amdgcn_s_setprio(1);
#pragma unroll
      for (int m2 = 0; m2 < 2; ++m2)
        accO[m2][ni] = __builtin_amdgcn_mfma_f32_16x16x32_f16(va[m2], u.f, accO[m2][ni], 0, 0, 0);
      __builtin_amdgcn_s_setprio(0);
    }
  }
  _Float16* pb = pin + ((size_t)b * NPOS) * DIMC + nh * 32 + g * 4;
#pragma unroll
  for (int ni = 0; ni < 2; ++ni) {
    _Float16* dst = pb + (size_t)(pbase + (n0 + ni) * 1024 + prow) * DIMC;
#pragma unroll
    for (int m2 = 0; m2 < 2; ++m2) {
      union { _Float16 h[4]; uint2 u; } pkk;
#pragma unroll
      for (int r = 0; r < 4; ++r) pkk.h[r] = (_Float16)accO[m2][ni][r];
      *(uint2*)(dst + m2 * 16) = pkk.u;
    }
  }
}

// ---------------------------------------------------------------------------
extern "C" void kernel_launch(void* const* d_in, const int* in_sizes, int n_in,
                              void* d_out, int out_size, void* d_ws, size_t ws_size,
                              hipStream_t stream) {
  const float* x      = (const float*)d_in[0];
  const float* w_qkv  = (const float*)d_in[2];
  const float* b_qkv  = (const float*)d_in[3];
  const float* w_off  = (const float*)d_in[4];
  const float* b_off  = (const float*)d_in[5];
  const float* w_sc   = (const float*)d_in[6];
  const float* b_sc   = (const float*)d_in[7];
  const float* w_proj = (const float*)d_in[8];
  const float* b_proj = (const float*)d_in[9];
  const float* rpb    = (const float*)d_in[10];
  float* out = (float*)d_out;
  char* wsp = (char*)d_ws;

  _Float16* qhb = (_Float16*)wsp;                       wsp += (size_t)BB * NPOS * 192 * 2;
  _Float16* kvh = (_Float16*)wsp;                       wsp += (size_t)BB * NPOS * 384 * 2;
  _Float16* xt  = (_Float16*)wsp;                       wsp += (size_t)BB * NPOS * DIMC * 2;
  _Float16* pin = xt;   // alias: xt dead after poolsc + qkv GEMM
  _Float16* whq = (_Float16*)wsp;                       wsp += (size_t)576 * DIMC * 2;
  _Float16* whp = (_Float16*)wsp;                       wsp += (size_t)DIMC * DIMC * 2;
  _Float16* biasL = (_Float16*)wsp;                     wsp += (size_t)6 * 2 * 4 * 64 * 8 * 2;
  float* offb   = (float*)wsp;                          wsp += (size_t)BB * NHH * 3 * NWTOT * 4;
  float* scb    = (float*)wsp;

  k_prepx<<<NTRX + 672, 256, 0, stream>>>(x, xt, w_qkv, w_proj, rpb, whq, whp, biasL);
  k_poolsc<<<BB * NWTOT, 256, 0, stream>>>(xt, w_off, b_off, w_sc, b_sc, offb, scb);
  k_gemm16<1><<<dim3(NPOS / 128, 576 / 64, BB), 256, 0, stream>>>(
      whq, b_qkv, xt, nullptr, qhb, kvh, 576, NPOS);
  k_sattn<<<3072, 128, 0, stream>>>(qhb, kvh, offb, scb, biasL, pin);
  k_gemm16<0><<<dim3(NPOS / 128, DIMC / 64, BB), 256, 0, stream>>>(
      whp, b_proj, pin, out, nullptr, nullptr, DIMC, NPOS);
}